// Round 1
// baseline (208.858 us; speedup 1.0000x reference)
//
#include <hip/hip_runtime.h>

// ElasticEmbedding: out[b,s,:] = residual_embedding[remap[x[b,s]]] if x in
// residual_index else pretrained_embedding[x[b,s]].
// D = 128 floats per row. Memory-bound gather; remap table built in d_ws.

#define EMB_D 128
#define LANES_PER_TOKEN 32   // 32 lanes x float4 = 128 floats
#define BLOCK_THREADS 256
#define TOK_PER_BLOCK (BLOCK_THREADS / LANES_PER_TOKEN)

__global__ void fill_remap_kernel(int* __restrict__ remap, int V) {
    int i = blockIdx.x * blockDim.x + threadIdx.x;
    if (i < V) remap[i] = -1;
}

__global__ void scatter_remap_kernel(int* __restrict__ remap,
                                     const int* __restrict__ ridx, int R) {
    int i = blockIdx.x * blockDim.x + threadIdx.x;
    if (i < R) remap[ridx[i]] = i;
}

__global__ void gather_kernel(const int* __restrict__ x,
                              const int* __restrict__ remap,
                              const float* __restrict__ pre,
                              const float* __restrict__ res,
                              float* __restrict__ out,
                              int n_tokens) {
    int token = blockIdx.x * TOK_PER_BLOCK + (threadIdx.x >> 5);
    int lane  = threadIdx.x & 31;
    if (token >= n_tokens) return;

    int t = x[token];          // broadcast load across the 32-lane group
    int r = remap[t];          // broadcast load

    const float4* src = (r >= 0)
        ? (const float4*)(res + (size_t)r * EMB_D)
        : (const float4*)(pre + (size_t)t * EMB_D);

    float4* dst = (float4*)out + (size_t)token * (EMB_D / 4);
    dst[lane] = src[lane];     // 16 B/lane coalesced copy
}

extern "C" void kernel_launch(void* const* d_in, const int* in_sizes, int n_in,
                              void* d_out, int out_size, void* d_ws, size_t ws_size,
                              hipStream_t stream) {
    const int*   x    = (const int*)d_in[0];          // [B*S] token ids
    const int*   ridx = (const int*)d_in[1];          // [R] sorted vocab ids
    const float* pre  = (const float*)d_in[2];        // [V, D]
    const float* res  = (const float*)d_in[3];        // [R, D]
    float*       out  = (float*)d_out;                // [B*S, D]

    const int n_tokens = in_sizes[0];
    const int R        = in_sizes[1];
    const int D        = in_sizes[3] / R;             // 128
    const int V        = in_sizes[2] / D;             // 100000
    (void)D; (void)ws_size;

    int* remap = (int*)d_ws;                          // V ints = 400 KB

    // 1. remap[v] = -1
    fill_remap_kernel<<<(V + 255) / 256, 256, 0, stream>>>(remap, V);
    // 2. remap[residual_index[i]] = i
    scatter_remap_kernel<<<(R + 255) / 256, 256, 0, stream>>>(remap, ridx, R);
    // 3. gather rows
    int grid = (n_tokens + TOK_PER_BLOCK - 1) / TOK_PER_BLOCK;
    gather_kernel<<<grid, BLOCK_THREADS, 0, stream>>>(x, remap, pre, res, out,
                                                      n_tokens);
}